// Round 1
// 139.911 us; speedup vs baseline: 1.0202x; 1.0202x over previous
//
#include <hip/hip_runtime.h>
#include <hip/hip_bf16.h>
#include <cstdint>

// Problem dims (fixed by reference)
#define B_  16
#define N_  32
#define L_  2048
#define D_  16
#define M_  32
#define K_  3
#define W_  2046   // (L - K)/STRIDE + 1

typedef __bf16 bf16x8 __attribute__((ext_vector_type(8)));
typedef float  f32x4  __attribute__((ext_vector_type(4)));

union frag_cast { uint4 u; bf16x8 f; };

// pack two fp32 -> one u32 holding two RTNE bf16 (a in low half)
__device__ __forceinline__ uint32_t pk2(float a, float b) {
    __hip_bfloat162 p = __float22bfloat162_rn(make_float2(a, b));
    union { __hip_bfloat162 h; uint32_t u; } cv; cv.h = p; return cv.u;
}

// ---------------------------------------------------------------------------
// Setup: transpose + scale weights into MFMA B-fragment order in d_ws.
// (ROUND-3/5 VERIFIED MAPPING — values unchanged; now one uint2 HALF per
// thread, 192 blocks x 64 thr = 2x waves, 4-deep load ILP each -> pure
// latency-bound kernel gets 2x TLP.)
// GEMM: K index κ = (k*32 + n)*4 + x  (k-major), col c = m*4 + d.
// ws layout: uint4[ct(8)][kc(12)][lane(64)]; lane's uint4 = 8 bf16 =
// B[κ = kc*32 + (lane>>4)*8 + j][col = ct*16 + (lane&15)], j = 0..7.
// half h covers j = h*4 .. h*4+3  (n = n0 + h, x = j&3).
// ---------------------------------------------------------------------------
__global__ __launch_bounds__(64) void caps_setup(const float* __restrict__ wp,
                                                 uint2* __restrict__ ws2) {
    const int gid  = blockIdx.x * 64 + threadIdx.x;   // 0..12287
    const int i    = gid >> 1;                        // uint4 index 0..6143
    const int half = gid & 1;
    const int ct   = i / 768;
    const int rem  = i - ct * 768;
    const int kc   = rem >> 6;
    const int lane = rem & 63;
    const int q    = lane >> 4;
    const int col  = (ct << 4) | (lane & 15);
    const int m = col >> 2, d = col & 3;
    const int k = kc >> 2;
    const int n = (kc & 3) * 8 + q * 2 + half;        // n0 + (j>>2)
    float f[4];
#pragma unroll
    for (int x = 0; x < 4; ++x)
        f[x] = wp[(((k * 32 + n) * 4 + x) * 4 + d) * 32 + m] * 0.03125f;
    uint2 o;
    o.x = pk2(f[0], f[1]); o.y = pk2(f[2], f[3]);
    ws2[i * 2 + half] = o;
}

// x LDS tile layout: byte addr = (n>>1)*1184 + w_local*64 + (e>>2)*16 + (n&1)*8
// (+ (e&3)*2 within the 8B granule).  18 w rows x 32 n, bf16.  The 16-B granule
// at (n2, w, a) holds elems a*4..a*4+3 of n=2*n2 then of n=2*n2+1 — exactly one
// MFMA A-frag uint4 per lane, so the K-loop A-load is ONE ds_read_b128 whose
// offset (kn*4736 + k*64 + rt*256) is a compile-time immediate.
#define XSTRIDE_N2 1184
#define XLDS_BYTES (16 * XSTRIDE_N2)   // 18944 B

// ---------------------------------------------------------------------------
// Main: block = 256 thr = 4 waves; block covers 16 w x all 128 cols.
// Wave: 64 rows (16 w x 4 a) x 32 cols (2 col-tiles: ct = wave*2 + cp).
// B held in 48 VGPR (2 ct x 6 kc), reloaded at the K-loop midpoint.
// K-loop: pure LDS + MFMA, no barriers, no global loads.
// Grid (128, 16); launch_bounds(256,4) -> <=128 VGPR, 4 blocks/CU (50%).
//
// R6 changes (latency attack; all verified layouts untouched):
//  - stage loads fully batched: ~10 float4 in flight, ONE exposed HBM latency
//  - stage writes PAIRED (n even+odd) -> full uint4 per lane, contiguous
//    16 B/lane: kills the 8-way bank conflict of the old stride-16 uint2 writes
//  - h=0 B-frags + gamma/beta hoisted before __syncthreads (hide under stage)
// ---------------------------------------------------------------------------
__global__ __launch_bounds__(256, 4) void caps_mfma(
    const float* __restrict__ xp,   // [B][N][L][16]
    const uint4* __restrict__ ws,   // B frags
    const float* __restrict__ gp,   // [16]
    const float* __restrict__ bp,   // [16]
    float* __restrict__ out)        // [B][M][W][16]
{
    __shared__ __align__(16) unsigned char xs[XLDS_BYTES];

    const int tid  = threadIdx.x;
    const int wave = tid >> 6;
    const int lane = tid & 63;
    const int q    = lane >> 4;        // quad id
    const int l15  = lane & 15;
    const int dL   = lane & 3;         // d (out inner-of-4)
    const int msub = (lane >> 2) & 3;  // m within col-tile
    const int b    = blockIdx.y;
    const int Wb   = blockIdx.x * 16;  // block's first w
    const int ct0  = wave * 2;

    // ---- Phase 1a: ISSUE all stage loads (pair granules: n=2*n2 and 2*n2+1
    // at same (w,f4)), keep in registers.  1152 pair-granules / 256 thr. ----
    const float* xb = xp + (size_t)b * N_ * L_ * D_;
    float4 ra[5], rb[5];
    int    laddr[5];
#pragma unroll
    for (int i = 0; i < 5; ++i) {
        const int idx = i * 256 + tid;          // 0..1279, valid < 1152
        if (i < 4 || idx < 1152) {
            const int f4 = idx & 3;
            const int wn = idx >> 2;            // 0..287
            const int w  = wn % 18;
            const int n2 = wn / 18;             // 0..15
            int gw = Wb + w; if (gw > L_ - 1) gw = L_ - 1;   // clamp halo
            const float* p0 = xb + ((size_t)(2 * n2) * L_ + gw) * D_ + f4 * 4;
            ra[i] = *reinterpret_cast<const float4*>(p0);                    // n even
            rb[i] = *reinterpret_cast<const float4*>(p0 + (size_t)L_ * D_);  // n odd
            laddr[i] = n2 * XSTRIDE_N2 + w * 64 + f4 * 16;
        }
    }

    // ---- Phase 1b: hoist h=0 B-frags + gamma/beta (L2-hot, hide under stage)
    uint4 breg0[2][6];
#pragma unroll
    for (int cp = 0; cp < 2; ++cp)
#pragma unroll
        for (int j = 0; j < 6; ++j)
            breg0[cp][j] = ws[(ct0 + cp) * 768 + j * 64 + lane];

    float gmv[4], btv[4];
#pragma unroll
    for (int r = 0; r < 4; ++r) { gmv[r] = gp[r * 4 + dL]; btv[r] = bp[r * 4 + dL]; }

    // ---- Phase 1c: convert + write LDS.  Full uint4 per lane, contiguous
    // 16 B stride -> conflict-free ds_write_b128 (was 8-way on uint2). ----
#pragma unroll
    for (int i = 0; i < 5; ++i) {
        const int idx = i * 256 + tid;
        if (i < 4 || idx < 1152) {
            uint4 o;
            o.x = pk2(ra[i].x, ra[i].y); o.y = pk2(ra[i].z, ra[i].w);  // n even: bytes 0-7
            o.z = pk2(rb[i].x, rb[i].y); o.w = pk2(rb[i].z, rb[i].w);  // n odd : bytes 8-15
            *reinterpret_cast<uint4*>(&xs[laddr[i]]) = o;
        }
    }
    __syncthreads();

    f32x4 acc[4][2];
#pragma unroll
    for (int rt = 0; rt < 4; ++rt)
#pragma unroll
        for (int cp = 0; cp < 2; ++cp)
            acc[rt][cp] = (f32x4){0.f, 0.f, 0.f, 0.f};

    // Lane-dependent A base; everything kc/rt/k-dependent is an imm offset.
    const unsigned char* ap =
        &xs[q * XSTRIDE_N2 + (l15 >> 2) * 64 + (l15 & 3) * 16];

    // ---- h = 0: pure LDS + MFMA (bregs already resident) ----
#pragma unroll
    for (int j = 0; j < 6; ++j) {
        const int kc = j;
        const int k  = kc >> 2;            // tap
        const int kn = kc & 3;             // n-chunk
        bf16x8 afr[4];
#pragma unroll
        for (int rt = 0; rt < 4; ++rt) {
            frag_cast c;
            c.u = *reinterpret_cast<const uint4*>(ap + kn * 4736 + k * 64 + rt * 256);
            afr[rt] = c.f;
        }
#pragma unroll
        for (int cp = 0; cp < 2; ++cp) {
            frag_cast bc; bc.u = breg0[cp][j];
#pragma unroll
            for (int rt = 0; rt < 4; ++rt)
                acc[rt][cp] = __builtin_amdgcn_mfma_f32_16x16x32_bf16(
                    afr[rt], bc.f, acc[rt][cp], 0, 0, 0);
        }
    }

    // ---- midpoint reload (single L2-hot stall, overlapped across waves) ----
    uint4 breg1[2][6];
#pragma unroll
    for (int cp = 0; cp < 2; ++cp)
#pragma unroll
        for (int j = 0; j < 6; ++j)
            breg1[cp][j] = ws[(ct0 + cp) * 768 + (6 + j) * 64 + lane];

    // ---- h = 1 ----
#pragma unroll
    for (int j = 0; j < 6; ++j) {
        const int kc = 6 + j;
        const int k  = kc >> 2;
        const int kn = kc & 3;
        bf16x8 afr[4];
#pragma unroll
        for (int rt = 0; rt < 4; ++rt) {
            frag_cast c;
            c.u = *reinterpret_cast<const uint4*>(ap + kn * 4736 + k * 64 + rt * 256);
            afr[rt] = c.f;
        }
#pragma unroll
        for (int cp = 0; cp < 2; ++cp) {
            frag_cast bc; bc.u = breg1[cp][j];
#pragma unroll
            for (int rt = 0; rt < 4; ++rt)
                acc[rt][cp] = __builtin_amdgcn_mfma_f32_16x16x32_bf16(
                    afr[rt], bc.f, acc[rt][cp], 0, 0, 0);
        }
    }

    // Fused LayerNorm + store (R3/R5-VERIFIED). D layout: row = q*4 + r ->
    // (w_sub=q, a=r); col = l15 -> (m = ct*4+msub, d = dL).
#pragma unroll
    for (int rt = 0; rt < 4; ++rt) {
        const int wv = Wb + rt * 4 + q;
#pragma unroll
        for (int cp = 0; cp < 2; ++cp) {
            const f32x4 v = acc[rt][cp];
            float s  = v[0] + v[1] + v[2] + v[3];
            float sq = v[0]*v[0] + v[1]*v[1] + v[2]*v[2] + v[3]*v[3];
            s  += __shfl_xor(s, 1);  s  += __shfl_xor(s, 2);
            sq += __shfl_xor(sq, 1); sq += __shfl_xor(sq, 2);
            const float mu   = s * (1.f / 16.f);
            const float var  = sq * (1.f / 16.f) - mu * mu;
            const float rstd = rsqrtf(var + 1e-5f);
            if (wv < W_) {
                const int m = (ct0 + cp) * 4 + msub;
                float* op = out + ((size_t)(b * M_ + m) * W_ + wv) * D_ + dL;
#pragma unroll
                for (int r = 0; r < 4; ++r)
                    op[r * 4] = gmv[r] * (v[r] - mu) * rstd + btv[r];
            }
        }
    }
}

extern "C" void kernel_launch(void* const* d_in, const int* in_sizes, int n_in,
                              void* d_out, int out_size, void* d_ws, size_t ws_size,
                              hipStream_t stream) {
    const float* x  = (const float*)d_in[0];
    const float* w  = (const float*)d_in[1];
    const float* g  = (const float*)d_in[2];
    const float* be = (const float*)d_in[3];
    float* out = (float*)d_out;

    caps_setup<<<192, 64, 0, stream>>>(w, (uint2*)d_ws);
    caps_mfma<<<dim3(128, 16), 256, 0, stream>>>(
        x, (const uint4*)d_ws, g, be, out);
}

// Round 2
// 132.839 us; speedup vs baseline: 1.0745x; 1.0532x over previous
//
#include <hip/hip_runtime.h>
#include <hip/hip_bf16.h>
#include <cstdint>

// Problem dims (fixed by reference)
#define B_  16
#define N_  32
#define L_  2048
#define D_  16
#define M_  32
#define K_  3
#define W_  2046   // (L - K)/STRIDE + 1

typedef __bf16 bf16x8 __attribute__((ext_vector_type(8)));
typedef float  f32x4  __attribute__((ext_vector_type(4)));

union frag_cast { uint4 u; bf16x8 f; };

// pack two fp32 -> one u32 holding two RTNE bf16 (a in low half)
__device__ __forceinline__ uint32_t pk2(float a, float b) {
    __hip_bfloat162 p = __float22bfloat162_rn(make_float2(a, b));
    union { __hip_bfloat162 h; uint32_t u; } cv; cv.h = p; return cv.u;
}

// ---------------------------------------------------------------------------
// Setup: transpose + scale weights into MFMA B-fragment order in d_ws.
// (ROUND-3/5 VERIFIED MAPPING — values unchanged.)
// GEMM: K index κ = (k*32 + n)*4 + x  (k-major), col c = m*4 + d.
// ws layout: uint4[ct(8)][kc(12)][lane(64)]; lane's uint4 = 8 bf16 =
// B[κ = kc*32 + (lane>>4)*8 + j][col = ct*16 + (lane&15)], j = 0..7.
// half h covers j = h*4 .. h*4+3  (n = n0 + h, x = j&3).
// ---------------------------------------------------------------------------
__global__ __launch_bounds__(64) void caps_setup(const float* __restrict__ wp,
                                                 uint2* __restrict__ ws2) {
    const int gid  = blockIdx.x * 64 + threadIdx.x;   // 0..12287
    const int i    = gid >> 1;                        // uint4 index 0..6143
    const int half = gid & 1;
    const int ct   = i / 768;
    const int rem  = i - ct * 768;
    const int kc   = rem >> 6;
    const int lane = rem & 63;
    const int q    = lane >> 4;
    const int col  = (ct << 4) | (lane & 15);
    const int m = col >> 2, d = col & 3;
    const int k = kc >> 2;
    const int n = (kc & 3) * 8 + q * 2 + half;        // n0 + (j>>2)
    float f[4];
#pragma unroll
    for (int x = 0; x < 4; ++x)
        f[x] = wp[(((k * 32 + n) * 4 + x) * 4 + d) * 32 + m] * 0.03125f;
    uint2 o;
    o.x = pk2(f[0], f[1]); o.y = pk2(f[2], f[3]);
    ws2[i * 2 + half] = o;
}

// x LDS tile layout (per slab buffer): byte addr =
//   (n>>1)*1184 + w_local*64 + (e>>2)*16 + (n&1)*8   (+ (e&3)*2 in-granule)
// 18 w rows x 32 n, bf16.  One MFMA A-frag uint4 per lane; K-loop A-load is
// ONE ds_read_b128 with compile-time immediate offset.
#define XSTRIDE_N2 1184
#define XLDS_BYTES (16 * XSTRIDE_N2)   // 18944 B per buffer

// ---------------------------------------------------------------------------
// R7 restructure (latency amortization; all R3/R5-verified layouts untouched):
// grid (32,16) = 512 blocks; each block does 4 slabs x 16 w = 64 w, one b,
// all 128 cols.  Per-block serial chain (launch, x-load stall, B-frag stall)
// is now paid once per 4x work:
//  - breg[2][12] persistent in VGPR: ws loaded ONCE per block (was 8 stall
//    groups/block at slab granularity)
//  - slab s+1 x loads issued BEFORE slab s K-loop (sched_barrier-pinned);
//    HBM latency hides under 96 MFMAs + LN + stores
//  - double-buffered LDS, ONE __syncthreads per slab
// launch_bounds(256,2): ~200 VGPR budgeted, 2 blocks/CU = grid/256 exactly.
// ---------------------------------------------------------------------------
__global__ __launch_bounds__(256, 2) void caps_mfma(
    const float* __restrict__ xp,   // [B][N][L][16]
    const uint4* __restrict__ ws,   // B frags
    const float* __restrict__ gp,   // [16]
    const float* __restrict__ bp,   // [16]
    float* __restrict__ out)        // [B][M][W][16]
{
    __shared__ __align__(16) unsigned char xs[2 * XLDS_BYTES];

    const int tid  = threadIdx.x;
    const int wave = tid >> 6;
    const int lane = tid & 63;
    const int q    = lane >> 4;        // quad id
    const int l15  = lane & 15;
    const int dL   = lane & 3;         // d (out inner-of-4)
    const int msub = (lane >> 2) & 3;  // m within col-tile
    const int b    = blockIdx.y;
    const int W0   = blockIdx.x * 64;  // block's first w (64-w super-tile)
    const int ct0  = wave * 2;

    const float* xb = xp + (size_t)b * N_ * L_ * D_;

    // ---- per-thread stage geometry (slab-independent) ----
    int  goff[5];    // float offset of (n-pair, f4) within xb, w excluded
    int  lbase[5];   // LDS byte offset within a buffer
    int  wA[5];      // w row 0..17
    bool val[5];
#pragma unroll
    for (int i = 0; i < 5; ++i) {
        const int idx = i * 256 + tid;          // 0..1279, valid < 1152
        val[i] = (i < 4) || (idx < 1152);
        const int f4 = idx & 3;
        const int wn = idx >> 2;                // 0..287
        const int w  = wn % 18;
        const int n2 = wn / 18;                 // 0..15
        wA[i]    = w;
        lbase[i] = n2 * XSTRIDE_N2 + w * 64 + f4 * 16;
        goff[i]  = (2 * n2) * L_ * D_ + f4 * 4;
    }

    float4 ra[5], rb[5];

    // issue slab-s stage loads into registers (pair granule: n even + n odd)
    auto issue = [&](int s) {
#pragma unroll
        for (int i = 0; i < 5; ++i) if (val[i]) {
            int gw = W0 + s * 16 + wA[i];
            if (gw > L_ - 1) gw = L_ - 1;       // clamp halo
            const float* p0 = xb + goff[i] + (size_t)gw * D_;
            ra[i] = *reinterpret_cast<const float4*>(p0);                    // n even
            rb[i] = *reinterpret_cast<const float4*>(p0 + (size_t)L_ * D_);  // n odd
        }
    };
    // convert + write one full uint4 per lane (conflict-free ds_write_b128)
    auto wrlds = [&](int bufoff) {
#pragma unroll
        for (int i = 0; i < 5; ++i) if (val[i]) {
            uint4 o;
            o.x = pk2(ra[i].x, ra[i].y); o.y = pk2(ra[i].z, ra[i].w);  // n even
            o.z = pk2(rb[i].x, rb[i].y); o.w = pk2(rb[i].z, rb[i].w);  // n odd
            *reinterpret_cast<uint4*>(&xs[bufoff + lbase[i]]) = o;
        }
    };

    // ---- prologue: slab-0 loads + persistent B frags + gamma/beta ----
    issue(0);

    uint4 breg[2][12];                          // 96 VGPR, whole block life
#pragma unroll
    for (int cp = 0; cp < 2; ++cp)
#pragma unroll
        for (int kc = 0; kc < 12; ++kc)
            breg[cp][kc] = ws[(ct0 + cp) * 768 + kc * 64 + lane];

    float gmv[4], btv[4];
#pragma unroll
    for (int r = 0; r < 4; ++r) { gmv[r] = gp[r * 4 + dL]; btv[r] = bp[r * 4 + dL]; }

    wrlds(0);
    __syncthreads();

    // Lane-dependent A base; buffer/kc/rt offsets are compile-time immediates.
    const unsigned char* ap =
        &xs[q * XSTRIDE_N2 + (l15 >> 2) * 64 + (l15 & 3) * 16];

#pragma unroll
    for (int s = 0; s < 4; ++s) {
        const int cur = (s & 1) * XLDS_BYTES;

        if (s < 3) {
            issue(s + 1);                       // prefetch next slab -> regs
            __builtin_amdgcn_sched_barrier(0);  // pin issue point (no sinking)
        }

        f32x4 acc[4][2];
#pragma unroll
        for (int rt = 0; rt < 4; ++rt)
#pragma unroll
            for (int cp = 0; cp < 2; ++cp)
                acc[rt][cp] = (f32x4){0.f, 0.f, 0.f, 0.f};

        // ---- K-loop: pure LDS + MFMA, breg resident, no barriers ----
#pragma unroll
        for (int kc = 0; kc < 12; ++kc) {
            const int k  = kc >> 2;             // tap
            const int kn = kc & 3;              // n-chunk
            bf16x8 afr[4];
#pragma unroll
            for (int rt = 0; rt < 4; ++rt) {
                frag_cast c;
                c.u = *reinterpret_cast<const uint4*>(
                    ap + cur + kn * 4736 + k * 64 + rt * 256);
                afr[rt] = c.f;
            }
#pragma unroll
            for (int cp = 0; cp < 2; ++cp) {
                frag_cast bc; bc.u = breg[cp][kc];
#pragma unroll
                for (int rt = 0; rt < 4; ++rt)
                    acc[rt][cp] = __builtin_amdgcn_mfma_f32_16x16x32_bf16(
                        afr[rt], bc.f, acc[rt][cp], 0, 0, 0);
            }
        }

        // ---- fused LayerNorm + store (R3/R5-VERIFIED mapping) ----
        // D layout: row = q*4 + r -> (w_sub=q, a=r); col = l15 -> (m, d=dL).
#pragma unroll
        for (int rt = 0; rt < 4; ++rt) {
            const int wv = W0 + s * 16 + rt * 4 + q;
#pragma unroll
            for (int cp = 0; cp < 2; ++cp) {
                const f32x4 v = acc[rt][cp];
                float ss = v[0] + v[1] + v[2] + v[3];
                float sq = v[0]*v[0] + v[1]*v[1] + v[2]*v[2] + v[3]*v[3];
                ss += __shfl_xor(ss, 1); ss += __shfl_xor(ss, 2);
                sq += __shfl_xor(sq, 1); sq += __shfl_xor(sq, 2);
                const float mu   = ss * (1.f / 16.f);
                const float var  = sq * (1.f / 16.f) - mu * mu;
                const float rstd = rsqrtf(var + 1e-5f);
                if (wv < W_) {
                    const int m = (ct0 + cp) * 4 + msub;
                    float* op = out + ((size_t)(b * M_ + m) * W_ + wv) * D_ + dL;
#pragma unroll
                    for (int r = 0; r < 4; ++r)
                        op[r * 4] = gmv[r] * (v[r] - mu) * rstd + btv[r];
                }
            }
        }

        // ---- hand off next slab: write other buffer, single barrier ----
        if (s < 3) {
            wrlds(cur ^ XLDS_BYTES);
            __syncthreads();
        }
    }
}

extern "C" void kernel_launch(void* const* d_in, const int* in_sizes, int n_in,
                              void* d_out, int out_size, void* d_ws, size_t ws_size,
                              hipStream_t stream) {
    const float* x  = (const float*)d_in[0];
    const float* w  = (const float*)d_in[1];
    const float* g  = (const float*)d_in[2];
    const float* be = (const float*)d_in[3];
    float* out = (float*)d_out;

    caps_setup<<<192, 64, 0, stream>>>(w, (uint2*)d_ws);
    caps_mfma<<<dim3(32, 16), 256, 0, stream>>>(
        x, (const uint4*)d_ws, g, be, out);
}